// Round 3
// baseline (51.104 us; speedup 1.0000x reference)
//
#include <hip/hip_runtime.h>
#include <hip/hip_bf16.h>

typedef float f32x4 __attribute__((ext_vector_type(4)));
typedef float f32x16 __attribute__((ext_vector_type(16)));
typedef short s16x8 __attribute__((ext_vector_type(8)));
typedef unsigned int u32x4 __attribute__((ext_vector_type(4)));

__device__ __forceinline__ short f2bf(float v) {
    __hip_bfloat16 h = __float2bfloat16(v);
    return __builtin_bit_cast(short, h);
}
__device__ __forceinline__ unsigned cvtpk(float lo, float hi) {
    unsigned r;
    asm("v_cvt_pk_bf16_f32 %0, %1, %2" : "=v"(r) : "v"(lo), "v"(hi));
    return r;
}
// v_permlane32_swap_b32: x <- {x_lo, y_lo}, y <- {x_hi, y_hi}
__device__ __forceinline__ void swap32(unsigned &x, unsigned &y) {
    asm("v_permlane32_swap_b32 %0, %1" : "+v"(x), "+v"(y));
}

// Kernel 1: xa[a][k] = b1[k] + sum_d x[a][d]*W1[d][k];  yb[b][k] = sum_d y[b][d]*W1[128+d][k]
__global__ __launch_bounds__(128) void precompute_kernel(
    const float* __restrict__ x, const float* __restrict__ y,
    const float* __restrict__ W1, const float* __restrict__ b1,
    float* __restrict__ xa, float* __restrict__ yb)
{
    __shared__ float rows[8][128];
    const int bid = blockIdx.x;
    const int k = threadIdx.x;
    const bool is_x = bid < 128;
    const int r0 = (is_x ? bid : bid - 128) * 8;
    const float* src = (is_x ? x : y) + (size_t)r0 * 128;
    const float* w = is_x ? W1 : (W1 + 128 * 128);
#pragma unroll
    for (int r = 0; r < 8; ++r) rows[r][k] = src[r * 128 + k];
    __syncthreads();
    float acc[8];
    const float bias = is_x ? b1[k] : 0.0f;
#pragma unroll
    for (int r = 0; r < 8; ++r) acc[r] = bias;
    for (int d = 0; d < 128; ++d) {
        float wv = w[d * 128 + k];
#pragma unroll
        for (int r = 0; r < 8; ++r) acc[r] = fmaf(rows[r][d], wv, acc[r]);
    }
    float* dst = (is_x ? xa : yb) + (size_t)r0 * 128 + k;
#pragma unroll
    for (int r = 0; r < 8; ++r) dst[r * 128] = acc[r];
}

// Kernel 2: fused pairwise MLP. Layer-1 via slot-robust rank-1 MFMA:
//   S = splat(xa_col) * ones_row + Y   (A has xv in ALL 8 slots, B has a single
//   nonzero slot, constant across lanes -> correct under any fragment layout).
// Grid 512 x 256. bid>>3 = a_chunk (16 a's via LDS), wave's b-group = (bid&7)*4+wave.
__global__ __launch_bounds__(256, 2) void fused_kernel(
    const float* __restrict__ xa, const float* __restrict__ yb,
    const float* __restrict__ W2, const float* __restrict__ b2,
    const float* __restrict__ W3, const float* __restrict__ b3,
    const float* __restrict__ W4, const float* __restrict__ b4,
    float* __restrict__ out)
{
    __shared__ float xa_lds[16 * 128];

    const int tid = threadIdx.x;
    const int bid = blockIdx.x;
    const int a_chunk = bid >> 3;
    const int bq = bid & 7;
    const int wave = tid >> 6;
    const int lane = tid & 63;
    const int half = lane >> 5;
    const int m = lane & 31;
    const int bg = bq * 4 + wave;

    // ---- stage xa tile (16 rows x 128 f32 = 8 KB) ----
    {
        const f32x4* xsrc = (const f32x4*)(xa + (size_t)a_chunk * 16 * 128);
        f32x4* dst = (f32x4*)xa_lds;
        for (int i = tid; i < 16 * 32; i += 256) dst[i] = xsrc[i];
    }

    // ---- y rows in C-layout registers: Y[t][r] = yb[bg*32+m][32t + (r&3)+8*(r>>2)+4*half]
    f32x16 Y[4];
    {
        const float* yrow = yb + (size_t)(bg * 32 + m) * 128 + half * 4;
#pragma unroll
        for (int t = 0; t < 4; ++t)
#pragma unroll
            for (int g = 0; g < 4; ++g) {
                f32x4 v = *(const f32x4*)&yrow[t * 32 + g * 8];
                Y[t][4 * g + 0] = v.x; Y[t][4 * g + 1] = v.y;
                Y[t][4 * g + 2] = v.z; Y[t][4 * g + 3] = v.w;
            }
    }

    // ---- loop-invariant fragments ----
    // Layer2 A = W2^T: A[m'][k], m' = lane&31 (+32*mt), k = s*16 + half*8 + j
    s16x8 W2a[2][8];
#pragma unroll
    for (int mt = 0; mt < 2; ++mt)
#pragma unroll
        for (int s = 0; s < 8; ++s)
#pragma unroll
            for (int j = 0; j < 8; ++j)
                W2a[mt][s][j] = f2bf(W2[(s * 16 + half * 8 + j) * 64 + mt * 32 + m]);

    // Layer3 A = W3^T padded M 8->32
    s16x8 W3a[4];
#pragma unroll
    for (int s = 0; s < 4; ++s)
#pragma unroll
        for (int j = 0; j < 8; ++j)
            W3a[s][j] = (m < 8) ? f2bf(W3[(s * 16 + half * 8 + j) * 8 + m]) : (short)0;

    // "ones" B-fragment: single nonzero slot (half0, word0, low16) = bf16(1.0),
    // constant across lanes -> B[k0][n] = 1 for exactly one k0, all n.
    u32x4 ow = {0u, 0u, 0u, 0u};
    ow.x = (half == 0) ? 0x00003F80u : 0u;
    const s16x8 ones = __builtin_bit_cast(s16x8, ow);

    // layer-2 bias in C-layout register init (validated round 1)
    f32x16 b2v0, b2v1;
#pragma unroll
    for (int r = 0; r < 16; ++r) {
        int f = (r & 3) + 8 * (r >> 2) + 4 * half;
        b2v0[r] = b2[f];
        b2v1[r] = b2[f + 32];
    }
    float b3v[4], w4v[4];
#pragma unroll
    for (int j = 0; j < 4; ++j) {
        b3v[j] = b3[j + 4 * half];
        w4v[j] = W4[j + 4 * half];
    }
    const float b4s = b4[0];

    __syncthreads();

    float* outp = out + (size_t)(a_chunk * 16) * 1024 + bg * 32 + m;

    for (int ai = 0; ai < 16; ++ai) {
        f32x16 c20 = b2v0, c21 = b2v1;

#pragma unroll
        for (int t = 0; t < 4; ++t) {
            // S_tile rows 32t..32t+31 of h1-pre-relu, C-layout.
            float xv = xa_lds[ai * 128 + t * 32 + m];
            unsigned pk = cvtpk(xv, xv);            // bf16(xv) in both halves
            u32x4 aw; aw.x = pk; aw.y = pk; aw.z = pk; aw.w = pk;  // all 8 slots
            s16x8 af = __builtin_bit_cast(s16x8, aw);
            f32x16 S = __builtin_amdgcn_mfma_f32_32x32x16_bf16(af, ones, Y[t], 0, 0, 0);

            // f32 relu, then bf16 pack
            unsigned P[8];
#pragma unroll
            for (int i = 0; i < 8; ++i)
                P[i] = cvtpk(fmaxf(S[2 * i], 0.f), fmaxf(S[2 * i + 1], 0.f));

            // C-layout 32-row tile -> two L2 B-fragments (K-steps 2t, 2t+1)
            unsigned w0 = P[0], w2 = P[2]; swap32(w0, w2);
            unsigned w1 = P[1], w3 = P[3]; swap32(w1, w3);
            u32x4 q0; q0.x = w0; q0.y = w1; q0.z = w2; q0.w = w3;
            s16x8 bf0 = __builtin_bit_cast(s16x8, q0);
            unsigned v0 = P[4], v2 = P[6]; swap32(v0, v2);
            unsigned v1 = P[5], v3 = P[7]; swap32(v1, v3);
            u32x4 q1; q1.x = v0; q1.y = v1; q1.z = v2; q1.w = v3;
            s16x8 bf1 = __builtin_bit_cast(s16x8, q1);

            c20 = __builtin_amdgcn_mfma_f32_32x32x16_bf16(W2a[0][2 * t], bf0, c20, 0, 0, 0);
            c21 = __builtin_amdgcn_mfma_f32_32x32x16_bf16(W2a[1][2 * t], bf0, c21, 0, 0, 0);
            c20 = __builtin_amdgcn_mfma_f32_32x32x16_bf16(W2a[0][2 * t + 1], bf1, c20, 0, 0, 0);
            c21 = __builtin_amdgcn_mfma_f32_32x32x16_bf16(W2a[1][2 * t + 1], bf1, c21, 0, 0, 0);
        }

        // relu(h2) pack; P covers features mt0, Q mt1
        unsigned P[8], Q[8];
#pragma unroll
        for (int i = 0; i < 8; ++i) {
            P[i] = cvtpk(fmaxf(c20[2 * i], 0.f), fmaxf(c20[2 * i + 1], 0.f));
            Q[i] = cvtpk(fmaxf(c21[2 * i], 0.f), fmaxf(c21[2 * i + 1], 0.f));
        }
        s16x8 bf3[4];
        {
            unsigned w0 = P[0], w2 = P[2]; swap32(w0, w2);
            unsigned w1 = P[1], w3 = P[3]; swap32(w1, w3);
            u32x4 t; t.x = w0; t.y = w1; t.z = w2; t.w = w3;
            bf3[0] = __builtin_bit_cast(s16x8, t);
            unsigned v0 = P[4], v2 = P[6]; swap32(v0, v2);
            unsigned v1 = P[5], v3 = P[7]; swap32(v1, v3);
            u32x4 u; u.x = v0; u.y = v1; u.z = v2; u.w = v3;
            bf3[1] = __builtin_bit_cast(s16x8, u);
            unsigned a0 = Q[0], a2 = Q[2]; swap32(a0, a2);
            unsigned a1 = Q[1], a3 = Q[3]; swap32(a1, a3);
            u32x4 t2; t2.x = a0; t2.y = a1; t2.z = a2; t2.w = a3;
            bf3[2] = __builtin_bit_cast(s16x8, t2);
            unsigned e0 = Q[4], e2 = Q[6]; swap32(e0, e2);
            unsigned e1 = Q[5], e3 = Q[7]; swap32(e1, e3);
            u32x4 u2; u2.x = e0; u2.y = e1; u2.z = e2; u2.w = e3;
            bf3[3] = __builtin_bit_cast(s16x8, u2);
        }

        f32x16 c3 = {};
        c3[0] = b3v[0]; c3[1] = b3v[1]; c3[2] = b3v[2]; c3[3] = b3v[3];
#pragma unroll
        for (int s = 0; s < 4; ++s)
            c3 = __builtin_amdgcn_mfma_f32_32x32x16_bf16(W3a[s], bf3[s], c3, 0, 0, 0);

        // layer4: each lane has 4 of its pair's 8 h3 features (other 4 in lane^32)
        float p = fmaxf(c3[0], 0.f) * w4v[0] + fmaxf(c3[1], 0.f) * w4v[1]
                + fmaxf(c3[2], 0.f) * w4v[2] + fmaxf(c3[3], 0.f) * w4v[3];
        unsigned pu = __builtin_bit_cast(unsigned, p);
        unsigned pv = pu;
        asm("" : "+v"(pv));
        swap32(pu, pv);
        float r = __builtin_bit_cast(float, pu) + __builtin_bit_cast(float, pv) + b4s;
        if (half == 0)
            outp[(size_t)ai * 1024] = r;
    }
}

extern "C" void kernel_launch(void* const* d_in, const int* in_sizes, int n_in,
                              void* d_out, int out_size, void* d_ws, size_t ws_size,
                              hipStream_t stream) {
    const float* x  = (const float*)d_in[0];
    const float* y  = (const float*)d_in[1];
    const float* W1 = (const float*)d_in[2];
    const float* b1 = (const float*)d_in[3];
    const float* W2 = (const float*)d_in[4];
    const float* b2 = (const float*)d_in[5];
    const float* W3 = (const float*)d_in[6];
    const float* b3 = (const float*)d_in[7];
    const float* W4 = (const float*)d_in[8];
    const float* b4 = (const float*)d_in[9];
    float* out = (float*)d_out;

    float* xa = (float*)d_ws;              // 1024*128 f32
    float* yb = xa + 1024 * 128;           // 1024*128 f32

    precompute_kernel<<<dim3(256), dim3(128), 0, stream>>>(x, y, W1, b1, xa, yb);
    fused_kernel<<<dim3(512), dim3(256), 0, stream>>>(xa, yb, W2, b2, W3, b3, W4, b4, out);
}

// Round 5
// 43.104 us; speedup vs baseline: 1.1856x; 1.1856x over previous
//
#include <hip/hip_runtime.h>
#include <hip/hip_bf16.h>

typedef float f32x4 __attribute__((ext_vector_type(4)));
typedef float f32x16 __attribute__((ext_vector_type(16)));
typedef short s16x8 __attribute__((ext_vector_type(8)));
typedef unsigned int u32x4 __attribute__((ext_vector_type(4)));

__device__ __forceinline__ short f2bf(float v) {
    __hip_bfloat16 h = __float2bfloat16(v);
    return __builtin_bit_cast(short, h);
}
__device__ __forceinline__ unsigned cvtpk(float lo, float hi) {
    unsigned r;
    asm("v_cvt_pk_bf16_f32 %0, %1, %2" : "=v"(r) : "v"(lo), "v"(hi));
    return r;
}
// v_permlane32_swap_b32: x <- {x_lo, y_lo}, y <- {x_hi, y_hi}
__device__ __forceinline__ void swap32(unsigned &x, unsigned &y) {
    asm("v_permlane32_swap_b32 %0, %1" : "+v"(x), "+v"(y));
}

// Kernel 1: xa[a][k] = b1[k] + sum_d x[a][d]*W1[d][k];  yb[b][k] = sum_d y[b][d]*W1[128+d][k]
__global__ __launch_bounds__(128) void precompute_kernel(
    const float* __restrict__ x, const float* __restrict__ y,
    const float* __restrict__ W1, const float* __restrict__ b1,
    float* __restrict__ xa, float* __restrict__ yb)
{
    __shared__ float rows[8][128];
    const int bid = blockIdx.x;
    const int k = threadIdx.x;
    const bool is_x = bid < 128;
    const int r0 = (is_x ? bid : bid - 128) * 8;
    const float* src = (is_x ? x : y) + (size_t)r0 * 128;
    const float* w = is_x ? W1 : (W1 + 128 * 128);
#pragma unroll
    for (int r = 0; r < 8; ++r) rows[r][k] = src[r * 128 + k];
    __syncthreads();
    float acc[8];
    const float bias = is_x ? b1[k] : 0.0f;
#pragma unroll
    for (int r = 0; r < 8; ++r) acc[r] = bias;
    for (int d = 0; d < 128; ++d) {
        float wv = w[d * 128 + k];
#pragma unroll
        for (int r = 0; r < 8; ++r) acc[r] = fmaf(rows[r][d], wv, acc[r]);
    }
    float* dst = (is_x ? xa : yb) + (size_t)r0 * 128 + k;
#pragma unroll
    for (int r = 0; r < 8; ++r) dst[r * 128] = acc[r];
}

// Kernel 2: fused pairwise MLP. Layer-1 B-fragments built directly in VALU
// (r1-validated slot mapping): bfrag[s][j] = relu(xa[ai][s*16+h*8+j] + yb[row][s*16+h*8+j]),
// with y held in registers (loaded once) and x broadcast-read from LDS.
// Grid 512 x 256. a_chunk = bid>>3 (16 a's via LDS), wave b-group = (bid&7)*4+wave.
__global__ __launch_bounds__(256, 2) void fused_kernel(
    const float* __restrict__ xa, const float* __restrict__ yb,
    const float* __restrict__ W2, const float* __restrict__ b2,
    const float* __restrict__ W3, const float* __restrict__ b3,
    const float* __restrict__ W4, const float* __restrict__ b4,
    float* __restrict__ out)
{
    __shared__ float xa_lds[16 * 128];

    const int tid = threadIdx.x;
    const int bid = blockIdx.x;
    const int a_chunk = bid >> 3;        // 0..63, 16 a's each
    const int bq = bid & 7;
    const int wave = tid >> 6;
    const int lane = tid & 63;
    const int half = lane >> 5;
    const int m = lane & 31;
    const int bg = bq * 4 + wave;        // 0..31

    // ---- stage xa tile (16 rows x 128 f32 = 8 KB): two f32x4 per thread ----
    {
        const f32x4* xsrc = (const f32x4*)(xa + (size_t)a_chunk * 16 * 128);
        f32x4* dst = (f32x4*)xa_lds;
        dst[tid] = xsrc[tid];
        dst[tid + 256] = xsrc[tid + 256];
    }

    // ---- y row in B-fragment order (r1 slot mapping): yv[s][0..1] = yb[row][s*16+h*8 ..]
    f32x4 yv0[8], yv1[8];
    {
        const float* yrow = yb + (size_t)(bg * 32 + m) * 128 + half * 8;
#pragma unroll
        for (int s = 0; s < 8; ++s) {
            yv0[s] = *(const f32x4*)&yrow[s * 16];
            yv1[s] = *(const f32x4*)&yrow[s * 16 + 4];
        }
    }

    // ---- loop-invariant fragments ----
    // Layer2 A = W2^T: A[m'][k], m' = lane&31 (+32*mt), k = s*16 + half*8 + j
    s16x8 W2a[2][8];
#pragma unroll
    for (int mt = 0; mt < 2; ++mt)
#pragma unroll
        for (int s = 0; s < 8; ++s)
#pragma unroll
            for (int j = 0; j < 8; ++j)
                W2a[mt][s][j] = f2bf(W2[(s * 16 + half * 8 + j) * 64 + mt * 32 + m]);

    // Layer3 A = W3^T padded M 8->32
    s16x8 W3a[4];
#pragma unroll
    for (int s = 0; s < 4; ++s)
#pragma unroll
        for (int j = 0; j < 8; ++j)
            W3a[s][j] = (m < 8) ? f2bf(W3[(s * 16 + half * 8 + j) * 8 + m]) : (short)0;

    // biases as C-operands (fed to the FIRST MFMA of each chain - zero movs/ai)
    f32x16 b2v0, b2v1, c3init;
#pragma unroll
    for (int r = 0; r < 16; ++r) {
        int f = (r & 3) + 8 * (r >> 2) + 4 * half;
        b2v0[r] = b2[f];
        b2v1[r] = b2[f + 32];
        c3init[r] = (r < 4) ? b3[(r & 3) + 4 * half] : 0.0f;
    }
    float w4v[4];
#pragma unroll
    for (int j = 0; j < 4; ++j) w4v[j] = W4[j + 4 * half];
    const float b4s = b4[0];

    __syncthreads();

    float* outp = out + (size_t)(a_chunk * 16) * 1024 + bg * 32 + m;

    for (int ai = 0; ai < 16; ++ai) {
        const float* xr = &xa_lds[ai * 128 + half * 8];
        f32x16 c20, c21;
#pragma unroll
        for (int s = 0; s < 8; ++s) {
            // layer-1 B-fragment, built in f32 VALU (wave-uniform x broadcast reads)
            f32x4 x0 = *(const f32x4*)&xr[s * 16];
            f32x4 x1 = *(const f32x4*)&xr[s * 16 + 4];
            f32x4 h0 = x0 + yv0[s];
            f32x4 h1 = x1 + yv1[s];
            u32x4 q;
            q.x = cvtpk(fmaxf(h0.x, 0.f), fmaxf(h0.y, 0.f));
            q.y = cvtpk(fmaxf(h0.z, 0.f), fmaxf(h0.w, 0.f));
            q.z = cvtpk(fmaxf(h1.x, 0.f), fmaxf(h1.y, 0.f));
            q.w = cvtpk(fmaxf(h1.z, 0.f), fmaxf(h1.w, 0.f));
            s16x8 bfrag = __builtin_bit_cast(s16x8, q);
            if (s == 0) {   // bias enters as the C operand of the first MFMA
                c20 = __builtin_amdgcn_mfma_f32_32x32x16_bf16(W2a[0][0], bfrag, b2v0, 0, 0, 0);
                c21 = __builtin_amdgcn_mfma_f32_32x32x16_bf16(W2a[1][0], bfrag, b2v1, 0, 0, 0);
            } else {
                c20 = __builtin_amdgcn_mfma_f32_32x32x16_bf16(W2a[0][s], bfrag, c20, 0, 0, 0);
                c21 = __builtin_amdgcn_mfma_f32_32x32x16_bf16(W2a[1][s], bfrag, c21, 0, 0, 0);
            }
        }

        // relu(h2) pack; P covers features mt0, Q mt1
        unsigned P[8], Q[8];
#pragma unroll
        for (int i = 0; i < 8; ++i) {
            P[i] = cvtpk(fmaxf(c20[2 * i], 0.f), fmaxf(c20[2 * i + 1], 0.f));
            Q[i] = cvtpk(fmaxf(c21[2 * i], 0.f), fmaxf(c21[2 * i + 1], 0.f));
        }
        // C-layout -> layer-3 B-fragments (validated r1/r3)
        s16x8 bf3[4];
        {
            unsigned w0 = P[0], w2 = P[2]; swap32(w0, w2);
            unsigned w1 = P[1], w3 = P[3]; swap32(w1, w3);
            u32x4 t; t.x = w0; t.y = w1; t.z = w2; t.w = w3;
            bf3[0] = __builtin_bit_cast(s16x8, t);
            unsigned v0 = P[4], v2 = P[6]; swap32(v0, v2);
            unsigned v1 = P[5], v3 = P[7]; swap32(v1, v3);
            u32x4 u; u.x = v0; u.y = v1; u.z = v2; u.w = v3;
            bf3[1] = __builtin_bit_cast(s16x8, u);
            unsigned a0 = Q[0], a2 = Q[2]; swap32(a0, a2);
            unsigned a1 = Q[1], a3 = Q[3]; swap32(a1, a3);
            u32x4 t2; t2.x = a0; t2.y = a1; t2.z = a2; t2.w = a3;
            bf3[2] = __builtin_bit_cast(s16x8, t2);
            unsigned e0 = Q[4], e2 = Q[6]; swap32(e0, e2);
            unsigned e1 = Q[5], e3 = Q[7]; swap32(e1, e3);
            u32x4 u2; u2.x = e0; u2.y = e1; u2.z = e2; u2.w = e3;
            bf3[3] = __builtin_bit_cast(s16x8, u2);
        }

        f32x16 c3 = __builtin_amdgcn_mfma_f32_32x32x16_bf16(W3a[0], bf3[0], c3init, 0, 0, 0);
#pragma unroll
        for (int s = 1; s < 4; ++s)
            c3 = __builtin_amdgcn_mfma_f32_32x32x16_bf16(W3a[s], bf3[s], c3, 0, 0, 0);

        // layer4: each lane has 4 of its pair's 8 h3 features (other 4 in lane^32)
        float p = fmaxf(c3[0], 0.f) * w4v[0] + fmaxf(c3[1], 0.f) * w4v[1]
                + fmaxf(c3[2], 0.f) * w4v[2] + fmaxf(c3[3], 0.f) * w4v[3];
        unsigned pu = __builtin_bit_cast(unsigned, p);
        unsigned pv = pu;
        asm("" : "+v"(pv));
        swap32(pu, pv);
        float r = __builtin_bit_cast(float, pu) + __builtin_bit_cast(float, pv) + b4s;
        if (half == 0)
            outp[(size_t)ai * 1024] = r;
    }
}

extern "C" void kernel_launch(void* const* d_in, const int* in_sizes, int n_in,
                              void* d_out, int out_size, void* d_ws, size_t ws_size,
                              hipStream_t stream) {
    const float* x  = (const float*)d_in[0];
    const float* y  = (const float*)d_in[1];
    const float* W1 = (const float*)d_in[2];
    const float* b1 = (const float*)d_in[3];
    const float* W2 = (const float*)d_in[4];
    const float* b2 = (const float*)d_in[5];
    const float* W3 = (const float*)d_in[6];
    const float* b3 = (const float*)d_in[7];
    const float* W4 = (const float*)d_in[8];
    const float* b4 = (const float*)d_in[9];
    float* out = (float*)d_out;

    float* xa = (float*)d_ws;              // 1024*128 f32
    float* yb = xa + 1024 * 128;           // 1024*128 f32

    precompute_kernel<<<dim3(256), dim3(128), 0, stream>>>(x, y, W1, b1, xa, yb);
    fused_kernel<<<dim3(512), dim3(256), 0, stream>>>(xa, yb, W2, b2, W3, b3, W4, b4, out);
}